// Round 5
// baseline (746.406 us; speedup 1.0000x reference)
//
#include <hip/hip_runtime.h>

#define DTC 0.02f
#define INV_DT_SKIP 2.5f            // 1/(0.02*20)
#define NBLK 32
#define NSTEP 50

typedef __attribute__((ext_vector_type(8))) __bf16 bf16x8;
typedef __attribute__((ext_vector_type(4))) float f32x4;
typedef unsigned long long u64t;

// Native RNE conversions (compiler emits v_cvt_pk_bf16_f32 for pairs --
// bit-identical to the old manual round-to-nearest-even bit twiddling,
// at ~1/6 the VALU ops).
__device__ inline unsigned pack2(float a, float b) {
    unsigned short ua = __builtin_bit_cast(unsigned short, (__bf16)a);
    unsigned short ub = __builtin_bit_cast(unsigned short, (__bf16)b);
    return (unsigned)ua | ((unsigned)ub << 16);
}
// Agent-scoped (cross-XCD, coherence-point) RELAXED accesses. Ordering is
// carried by per-wave vmcnt(0) drains before the arrival count that gates
// the flag publish, plus a compiler barrier after poll success.
__device__ inline void gstore32(unsigned* p, unsigned v) {
    __hip_atomic_store(p, v, __ATOMIC_RELAXED, __HIP_MEMORY_SCOPE_AGENT);
}
__device__ inline unsigned gload32(const unsigned* p) {
    return __hip_atomic_load(p, __ATOMIC_RELAXED, __HIP_MEMORY_SCOPE_AGENT);
}
__device__ inline u64t gload64(const u64t* p) {
    return __hip_atomic_load(p, __ATOMIC_RELAXED, __HIP_MEMORY_SCOPE_AGENT);
}
// Pin a 16B fragment into VGPRs: opaque def prevents the allocator from
// rematerializing the global load + bf16 conversion every loop iteration.
#define PINV(x) asm volatile("" : "+v"(x))

// ---------------------------------------------------------------------------
// Neumann inverses (verified). inv1 = (I-dt*Ap)^-1, inv2 = (3I-2dt*Ap)^-1.
// ---------------------------------------------------------------------------
__global__ __launch_bounds__(256) void kinv(const float* __restrict__ Ap,
                                            float* __restrict__ inv1,
                                            float* __restrict__ inv2) {
    const int t = threadIdx.x;
    const float coef  = (blockIdx.x == 0) ? DTC : (2.0f * DTC / 3.0f);
    const float scale = (blockIdx.x == 0) ? 1.0f : (1.0f / 3.0f);
    float* outp = (blockIdx.x == 0) ? inv1 : inv2;

    __shared__ float ET[64 * 68];
    __shared__ float XA[64 * 68];
    __shared__ float XB[64 * 68];

    for (int idx = t; idx < 4096; idx += 256) {
        int r = idx >> 6, c = idx & 63;
        float e = coef * Ap[idx];
        ET[c * 68 + r] = e;
        XA[r * 68 + c] = ((r == c) ? 1.0f : 0.0f) + e;
    }
    __syncthreads();

    const int rr = (t >> 4) << 2;
    const int cc = (t & 15) << 2;
    float* bufs[2] = {XA, XB};
    for (int it = 0; it < 3; it++) {
        const float* Xin = bufs[it & 1];
        float* Xout = bufs[(it + 1) & 1];
        float acc[4][4];
        #pragma unroll
        for (int i = 0; i < 4; i++)
            #pragma unroll
            for (int j = 0; j < 4; j++)
                acc[i][j] = ((rr + i) == (cc + j)) ? 1.0f : 0.0f;
        for (int k = 0; k < 64; k++) {
            float4 e4 = *(const float4*)&ET[k * 68 + rr];
            float4 x4 = *(const float4*)&Xin[k * 68 + cc];
            float ev[4] = {e4.x, e4.y, e4.z, e4.w};
            float xv[4] = {x4.x, x4.y, x4.z, x4.w};
            #pragma unroll
            for (int i = 0; i < 4; i++)
                #pragma unroll
                for (int j = 0; j < 4; j++)
                    acc[i][j] += ev[i] * xv[j];
        }
        __syncthreads();
        #pragma unroll
        for (int i = 0; i < 4; i++)
            #pragma unroll
            for (int j = 0; j < 4; j++)
                Xout[(rr + i) * 68 + cc + j] = acc[i][j];
        __syncthreads();
    }
    const float* Xf = bufs[1];
    for (int idx = t; idx < 4096; idx += 256) {
        int r = idx >> 6, c = idx & 63;
        outp[idx] = scale * Xf[r * 68 + c];
    }
}

__global__ void kzero(unsigned* __restrict__ flags) {
    if (threadIdx.x < NBLK) flags[threadIdx.x] = 0u;
}

// ---------------------------------------------------------------------------
// Persistent kernel, 32 blocks. Champion (r0) protocol: bf16-pair slots,
// parity double-buffered; flag publish; all-wave poll; single-burst 32-slot
// gather. Changes vs r0 (intra-block only, transport untouched):
//   - native __bf16 casts (v_cvt_pk) replace manual f2bf chains everywhere
//     hot (phase A hi/lo, ff repack, pack2, phase B rhi/rlo).
//   - post-reduce __syncthreads replaced by per-wave vmcnt(0) drain + LDS
//     arrival counter; thread 0 spins (counter==8*(k+1)) then publishes the
//     flag. Same visibility guarantee (every wave's stores drained before
//     flag issue), but wave drains overlap and no full-block barrier.
//   - rbase (BDF2 base) hoisted between arrival and poll.
// WAR safety across parity reuse: flags[Y] >= k+1 implies every wave of Y
// arrived for step k, which (program order) implies it finished its
// step-(k-1) gather; stores for step k+1 overwrite parity data of step k-1,
// so no block can still be reading them.
// ---------------------------------------------------------------------------
__global__ __launch_bounds__(512, 2)
void kmain(const float* __restrict__ state,
           const float* __restrict__ Wu,
           const float* __restrict__ Wv,
           const float* __restrict__ Pp,
           const float* __restrict__ inv1,
           const float* __restrict__ inv2,
           unsigned* __restrict__ pbuf,     // 2 parities x 32 slots x 1024 u32
           unsigned* __restrict__ flags,    // NBLK flag words
           float* __restrict__ out) {
    const int t = threadIdx.x;
    const int l = t & 63;
    const int w = t >> 6;                 // wave 0..7
    const int blk = blockIdx.x;
    const int gw = blk * 8 + w;           // 0..255
    const bool active = (gw < 250);       // waves 250..255 idle in phase A

    __shared__ float Ab[3][2176];         // a triple buffer, 32 rows x 68
    __shared__ float fb[8][16][36];       // per-wave f tile (K=32 + pad)
    __shared__ float red2[2][8][1056];    // per-mt, per-wave proj partials (q4 stride 264)
    __shared__ float rbuf[32 * 68];       // r, padded stride 68
    __shared__ unsigned arr;              // cumulative wave-arrival counter

    for (int i = t; i < 2048; i += 512) Ab[0][(i >> 6) * 68 + (i & 63)] = state[i];
    if (t == 0) arr = 0u;
    if (!active) {                        // idle waves' red2 stays zero forever
        for (int i = l; i < 1056; i += 64) { red2[0][w][i] = 0.f; red2[1][w][i] = 0.f; }
    }

    const int nr = l & 15;
    const int c0 = (l >> 4) << 3;
    const int cA = gw * 2;                 // chunk ids (cA,cA+1), same net
    const float* W = (cA < 250) ? Wu : Wv;
    const int glA = ((cA < 250) ? cA : cA - 250) * 32;

    // ---- persistent fragments, pinned into VGPRs ----
    bf16x8 wf[2][2][4][2], pf[2][4], sfw[2];
    if (active) {
        #pragma unroll
        for (int ch = 0; ch < 2; ch++)
            #pragma unroll
            for (int th = 0; th < 2; th++)
                #pragma unroll
                for (int rb = 0; rb < 4; rb++)
                    #pragma unroll
                    for (int kt = 0; kt < 2; kt++) {
                        const float* s = W + (size_t)(rb * 8000 + glA + ch * 32 + th * 16 + nr) * 64
                                           + kt * 32 + c0;
                        bf16x8 o;
                        #pragma unroll
                        for (int j = 0; j < 8; j++) o[j] = (__bf16)s[j];
                        wf[ch][th][rb][kt] = o;
                    }
        #pragma unroll
        for (int ch = 0; ch < 2; ch++)
            #pragma unroll
            for (int pt = 0; pt < 4; pt++) {
                const float* s = Pp + (size_t)(pt * 16 + nr) * 16000 + (cA + ch) * 32 + c0;
                bf16x8 o;
                #pragma unroll
                for (int j = 0; j < 8; j++) o[j] = (__bf16)s[j];
                pf[ch][pt] = o;
            }
    }
    {   // wave's solve tile: mtS = w>>2, ptS = w&3 ; S = inv2 - I/3
        const int ptS = w & 3;
        #pragma unroll
        for (int kt = 0; kt < 2; kt++) {
            int p = ptS * 16 + nr;
            const float* s = inv2 + (size_t)p * 64 + kt * 32 + c0;
            bf16x8 o;
            #pragma unroll
            for (int j = 0; j < 8; j++) {
                float v = s[j] - ((p == kt * 32 + c0 + j) ? (1.0f / 3.0f) : 0.0f);
                o[j] = (__bf16)v;
            }
            sfw[kt] = o;
        }
    }
    // pin everything (opaque defs -> no rematerialization inside the loop)
    #pragma unroll
    for (int ch = 0; ch < 2; ch++) {
        #pragma unroll
        for (int th = 0; th < 2; th++)
            #pragma unroll
            for (int rb = 0; rb < 4; rb++)
                #pragma unroll
                for (int kt = 0; kt < 2; kt++) PINV(wf[ch][th][rb][kt]);
        #pragma unroll
        for (int pt = 0; pt < 4; pt++) PINV(pf[ch][pt]);
    }
    PINV(sfw[0]); PINV(sfw[1]);
    __syncthreads();

    int ia_prev = 2, ia_cur = 0, ia_next = 1;
    float fprev[4];                       // f_prev for elems 4t..4t+3

    for (int k = 0; k < NSTEP; k++) {
        const int par = k & 1;
        unsigned* pslot = pbuf + (size_t)par * (NBLK * 1024) + blk * 1024;

        // ================= phase A: rhs partials =================
        if (active) {
            const int col = l & 15, q4 = l >> 4;
            #pragma unroll
            for (int mt = 0; mt < 2; mt++) {
                bf16x8 ahi[2], alo[2];
                {
                    const float* ac = Ab[ia_cur];
                    #pragma unroll
                    for (int kt = 0; kt < 2; kt++) {
                        bf16x8 hv, lv;
                        #pragma unroll
                        for (int j = 0; j < 8; j++) {
                            float x = ac[(mt * 16 + nr) * 68 + kt * 32 + c0 + j];
                            __bf16 h = (__bf16)x;
                            hv[j] = h;
                            lv[j] = (__bf16)(x - (float)h);
                        }
                        ahi[kt] = hv;
                        alo[kt] = lv;
                    }
                }
                f32x4 racc[4] = {{0.f,0.f,0.f,0.f},{0.f,0.f,0.f,0.f},
                                 {0.f,0.f,0.f,0.f},{0.f,0.f,0.f,0.f}};
                #pragma unroll
                for (int ch = 0; ch < 2; ch++) {
                    #pragma unroll
                    for (int th = 0; th < 2; th++) {
                        f32x4 z[4];
                        #pragma unroll
                        for (int rb = 0; rb < 4; rb++) {
                            f32x4 acc = {0.f, 0.f, 0.f, 0.f};
                            #pragma unroll
                            for (int kt = 0; kt < 2; kt++) {
                                acc = __builtin_amdgcn_mfma_f32_16x16x32_bf16(ahi[kt], wf[ch][th][rb][kt], acc, 0, 0, 0);
                                acc = __builtin_amdgcn_mfma_f32_16x16x32_bf16(alo[kt], wf[ch][th][rb][kt], acc, 0, 0, 0);
                            }
                            z[rb] = acc;
                        }
                        #pragma unroll
                        for (int r = 0; r < 4; r++) {
                            float f = z[0][r] * z[2][r] + z[1][r] * z[3][r];
                            fb[w][q4 * 4 + r][th * 16 + col] = f;   // intra-wave only
                        }
                    }
                    bf16x8 ff;
                    #pragma unroll
                    for (int j = 0; j < 8; j++) ff[j] = (__bf16)fb[w][nr][c0 + j];
                    #pragma unroll
                    for (int pt = 0; pt < 4; pt++)
                        racc[pt] = __builtin_amdgcn_mfma_f32_16x16x32_bf16(ff, pf[ch][pt], racc[pt], 0, 0, 0);
                }
                #pragma unroll
                for (int pt = 0; pt < 4; pt++)
                    #pragma unroll
                    for (int r = 0; r < 4; r++)
                        red2[mt][w][q4 * 264 + r * 64 + pt * 16 + col] = racc[pt][r];
            }
        }
        __syncthreads();

        // block partial (2048 elems) -> packed bf16 pairs, one slot
        {
            const int q4e = t >> 7;
            const int rem = (2 * t) & 255;
            const int addr = q4e * 264 + rem;
            #pragma unroll
            for (int mt = 0; mt < 2; mt++) {
                float s0 = 0.f, s1 = 0.f;
                #pragma unroll
                for (int w8 = 0; w8 < 8; w8++) {
                    float2 p = *(const float2*)&red2[mt][w8][addr];
                    s0 += p.x;
                    s1 += p.y;
                }
                gstore32(&pslot[mt * 512 + t], pack2(s0, s1));
            }
        }

        // per-wave drain + LDS arrival (replaces full-block barrier+drain)
        asm volatile("s_waitcnt vmcnt(0)" ::: "memory");
        if (l == 0) atomicAdd(&arr, 1u);
        if (t == 0) {   // publish as soon as ALL waves' stores are drained
            while (__hip_atomic_load(&arr, __ATOMIC_RELAXED,
                                     __HIP_MEMORY_SCOPE_WORKGROUP) < 8u * (k + 1))
                ;
            gstore32(&flags[blk], (unsigned)(k + 1));
        }

        // rbase hoist: hides under flag flight / poll
        float rb_[4];
        const int bB = (4 * t) >> 6, p0B = (4 * t) & 63;
        {
            #pragma unroll
            for (int jj = 0; jj < 4; jj++) {
                int row = bB * 68 + p0B + jj;
                float av = Ab[ia_cur][row];
                rb_[jj] = (k == 0) ? av
                                   : (4.f * av - Ab[ia_prev][row] - 2.f * DTC * fprev[jj]);
            }
        }

        // all-wave poll of the 32 flags (r0 form)
        {
            const unsigned target = (unsigned)(k + 1);
            for (;;) {
                unsigned v = gload32(&flags[l & (NBLK - 1)]);
                if (__all(v >= target)) break;
                __builtin_amdgcn_s_sleep(1);
            }
            asm volatile("" ::: "memory");     // keep gather below the poll
        }

        // ========= redundant reduce: f elems 4t..4t+3 = -sum over 32 slots =========
        float fv[4];
        {
            const u64t* pb = (const u64t*)(pbuf + (size_t)par * (NBLK * 1024));
            float s0 = 0.f, s1 = 0.f, s2 = 0.f, s3 = 0.f;
            #pragma unroll
            for (int s = 0; s < NBLK; s++) {
                u64t v = gload64(pb + (size_t)s * 512 + t);
                unsigned lo = (unsigned)v, hi = (unsigned)(v >> 32);
                s0 += __uint_as_float(lo << 16);
                s1 += __uint_as_float(lo & 0xffff0000u);
                s2 += __uint_as_float(hi << 16);
                s3 += __uint_as_float(hi & 0xffff0000u);
            }
            fv[0] = -s0; fv[1] = -s1; fv[2] = -s2; fv[3] = -s3;
        }

        // ================= phase B: BDF2 combine + distributed solve =================
        {
            const float cf = (k == 0) ? DTC : 4.f * DTC;
            #pragma unroll
            for (int jj = 0; jj < 4; jj++) {
                float f = fv[jj];
                rbuf[bB * 68 + p0B + jj] = rb_[jj] + cf * f;
                fprev[jj] = f;
            }
        }
        __syncthreads();

        {   // wave (mtS = w>>2, ptS = w&3): a_next tile = cb*r + (r @ S^T) tile
            const int mtS = w >> 2, ptS = w & 3;
            const int col = l & 15, q4 = l >> 4;
            bf16x8 S0, S1;
            float cb;
            if (k == 0) {                   // S1 = inv1 - I, cb = 1 (once)
                #pragma unroll
                for (int kt = 0; kt < 2; kt++) {
                    int p = ptS * 16 + nr;
                    const float* s = inv1 + (size_t)p * 64 + kt * 32 + c0;
                    bf16x8 o;
                    #pragma unroll
                    for (int j = 0; j < 8; j++) {
                        float v = s[j] - ((p == kt * 32 + c0 + j) ? 1.0f : 0.0f);
                        o[j] = (__bf16)v;
                    }
                    if (kt == 0) S0 = o;
                    else         S1 = o;
                }
                cb = 1.0f;
            } else {
                S0 = sfw[0]; S1 = sfw[1];
                cb = 1.0f / 3.0f;
            }
            bf16x8 rhi[2], rlo[2];
            #pragma unroll
            for (int kt = 0; kt < 2; kt++) {
                bf16x8 hv, lv;
                #pragma unroll
                for (int j = 0; j < 8; j++) {
                    float x = rbuf[(mtS * 16 + nr) * 68 + kt * 32 + c0 + j];
                    __bf16 h = (__bf16)x;
                    hv[j] = h;
                    lv[j] = (__bf16)(x - (float)h);
                }
                rhi[kt] = hv;
                rlo[kt] = lv;
            }
            f32x4 acc;
            #pragma unroll
            for (int r = 0; r < 4; r++)
                acc[r] = rbuf[(mtS * 16 + q4 * 4 + r) * 68 + ptS * 16 + col] * cb;
            acc = __builtin_amdgcn_mfma_f32_16x16x32_bf16(rhi[0], S0, acc, 0, 0, 0);
            acc = __builtin_amdgcn_mfma_f32_16x16x32_bf16(rlo[0], S0, acc, 0, 0, 0);
            acc = __builtin_amdgcn_mfma_f32_16x16x32_bf16(rhi[1], S1, acc, 0, 0, 0);
            acc = __builtin_amdgcn_mfma_f32_16x16x32_bf16(rlo[1], S1, acc, 0, 0, 0);
            #pragma unroll
            for (int r = 0; r < 4; r++)
                Ab[ia_next][(mtS * 16 + q4 * 4 + r) * 68 + ptS * 16 + col] = acc[r];
        }
        __syncthreads();

        if (k == NSTEP - 1 && blk == 0) {
            for (int i = t; i < 2048; i += 512)
                out[i] = (Ab[ia_next][(i >> 6) * 68 + (i & 63)] - state[i]) * INV_DT_SKIP;
        }

        int tmp = ia_prev; ia_prev = ia_cur; ia_cur = ia_next; ia_next = tmp;
    }
}

// ---------------------------------------------------------------------------
extern "C" void kernel_launch(void* const* d_in, const int* in_sizes, int n_in,
                              void* d_out, int out_size, void* d_ws, size_t ws_size,
                              hipStream_t stream) {
    const float* state = (const float*)d_in[0];   // (32, 64)
    const float* Ap    = (const float*)d_in[1];   // (64, 64)
    const float* Wu    = (const float*)d_in[2];   // (32000, 64)
    const float* Wv    = (const float*)d_in[3];   // (32000, 64)
    const float* Pp    = (const float*)d_in[4];   // (64, 16000)
    float* out = (float*)d_out;
    float* ws  = (float*)d_ws;

    float* inv1 = ws;                               // 4096 floats
    float* inv2 = ws + 4096;                        // 4096 floats
    unsigned* flags = (unsigned*)(ws + 8192);       // NBLK u32 (pad to 64)
    unsigned* pbuf  = (unsigned*)(ws + 8192 + 64);  // 2 x 32 x 1024 u32

    hipLaunchKernelGGL(kzero, dim3(1), dim3(64), 0, stream, flags);
    hipLaunchKernelGGL(kinv, dim3(2), dim3(256), 0, stream, Ap, inv1, inv2);
    hipLaunchKernelGGL(kmain, dim3(NBLK), dim3(512), 0, stream,
                       state, Wu, Wv, Pp, inv1, inv2, pbuf, flags, out);
}

// Round 6
// 713.829 us; speedup vs baseline: 1.0456x; 1.0456x over previous
//
#include <hip/hip_runtime.h>

#define DTC 0.02f
#define INV_DT_SKIP 2.5f            // 1/(0.02*20)
#define NBLK 32
#define NSTEP 50

typedef __attribute__((ext_vector_type(8))) __bf16 bf16x8;
typedef __attribute__((ext_vector_type(4))) float f32x4;
typedef unsigned long long u64t;

// Native RNE fp32->bf16 (compiler emits v_cvt_pk_bf16_f32 pairs; bit-
// identical rounding to the old manual bit-twiddled f2bf at ~1/4 the VALU).
__device__ inline unsigned pack2(float a, float b) {
    unsigned short ua = __builtin_bit_cast(unsigned short, (__bf16)a);
    unsigned short ub = __builtin_bit_cast(unsigned short, (__bf16)b);
    return (unsigned)ua | ((unsigned)ub << 16);
}
// Agent-scoped (cross-XCD, coherence-point) RELAXED accesses. Ordering is
// carried by the vmcnt(0) drain inside __syncthreads before flag publish,
// plus a compiler barrier after poll success (stops load hoisting).
__device__ inline void gstore32(unsigned* p, unsigned v) {
    __hip_atomic_store(p, v, __ATOMIC_RELAXED, __HIP_MEMORY_SCOPE_AGENT);
}
__device__ inline unsigned gload32(const unsigned* p) {
    return __hip_atomic_load(p, __ATOMIC_RELAXED, __HIP_MEMORY_SCOPE_AGENT);
}
__device__ inline u64t gload64(const u64t* p) {
    return __hip_atomic_load(p, __ATOMIC_RELAXED, __HIP_MEMORY_SCOPE_AGENT);
}
// Pin a 16B fragment into VGPRs: opaque def prevents the allocator from
// rematerializing the global load + bf16 conversion every loop iteration.
#define PINV(x) asm volatile("" : "+v"(x))

// ---------------------------------------------------------------------------
// Neumann inverses (verified). inv1 = (I-dt*Ap)^-1, inv2 = (3I-2dt*Ap)^-1.
// ---------------------------------------------------------------------------
__global__ __launch_bounds__(256) void kinv(const float* __restrict__ Ap,
                                            float* __restrict__ inv1,
                                            float* __restrict__ inv2) {
    const int t = threadIdx.x;
    const float coef  = (blockIdx.x == 0) ? DTC : (2.0f * DTC / 3.0f);
    const float scale = (blockIdx.x == 0) ? 1.0f : (1.0f / 3.0f);
    float* outp = (blockIdx.x == 0) ? inv1 : inv2;

    __shared__ float ET[64 * 68];
    __shared__ float XA[64 * 68];
    __shared__ float XB[64 * 68];

    for (int idx = t; idx < 4096; idx += 256) {
        int r = idx >> 6, c = idx & 63;
        float e = coef * Ap[idx];
        ET[c * 68 + r] = e;
        XA[r * 68 + c] = ((r == c) ? 1.0f : 0.0f) + e;
    }
    __syncthreads();

    const int rr = (t >> 4) << 2;
    const int cc = (t & 15) << 2;
    float* bufs[2] = {XA, XB};
    for (int it = 0; it < 3; it++) {
        const float* Xin = bufs[it & 1];
        float* Xout = bufs[(it + 1) & 1];
        float acc[4][4];
        #pragma unroll
        for (int i = 0; i < 4; i++)
            #pragma unroll
            for (int j = 0; j < 4; j++)
                acc[i][j] = ((rr + i) == (cc + j)) ? 1.0f : 0.0f;
        for (int k = 0; k < 64; k++) {
            float4 e4 = *(const float4*)&ET[k * 68 + rr];
            float4 x4 = *(const float4*)&Xin[k * 68 + cc];
            float ev[4] = {e4.x, e4.y, e4.z, e4.w};
            float xv[4] = {x4.x, x4.y, x4.z, x4.w};
            #pragma unroll
            for (int i = 0; i < 4; i++)
                #pragma unroll
                for (int j = 0; j < 4; j++)
                    acc[i][j] += ev[i] * xv[j];
        }
        __syncthreads();
        #pragma unroll
        for (int i = 0; i < 4; i++)
            #pragma unroll
            for (int j = 0; j < 4; j++)
                Xout[(rr + i) * 68 + cc + j] = acc[i][j];
        __syncthreads();
    }
    const float* Xf = bufs[1];
    for (int idx = t; idx < 4096; idx += 256) {
        int r = idx >> 6, c = idx & 63;
        outp[idx] = scale * Xf[r * 68 + c];
    }
}

__global__ void kzero(unsigned* __restrict__ flags) {
    if (threadIdx.x < NBLK) flags[threadIdx.x] = 0u;
}

// ---------------------------------------------------------------------------
// Persistent kernel, 32 blocks — CHAMPION (r0) protocol verbatim:
//   phase A MFMA partials -> block reduce -> bf16-pair slot (parity
//   double-buffered) -> __syncthreads (drains ALL waves' stores, vmcnt 0)
//   -> t0 flag publish -> rbase hoist -> ALL waves poll all 32 flags ->
//   single-burst 32-slot u64 gather -> BDF2 combine -> distributed solve.
// Intra-block-only changes vs r0 (r5 post-mortem isolated these as safe):
//   - native __bf16 casts replace manual f2bf chains (less VALU, same bits)
//   - rbase (BDF2 base term) hoisted between publish and poll
//   - float2 LDS reads in the block reduce (same addresses, half the ops)
// pbuf parity WAR safety: observing flag(k+1) from every block implies that
// block finished its step-k gather (program order + vmcnt drain), which
// last read parity(k+1).
// ---------------------------------------------------------------------------
__global__ __launch_bounds__(512, 2)
void kmain(const float* __restrict__ state,
           const float* __restrict__ Wu,
           const float* __restrict__ Wv,
           const float* __restrict__ Pp,
           const float* __restrict__ inv1,
           const float* __restrict__ inv2,
           unsigned* __restrict__ pbuf,     // 2 parities x 32 slots x 1024 u32
           unsigned* __restrict__ flags,    // NBLK flag words
           float* __restrict__ out) {
    const int t = threadIdx.x;
    const int l = t & 63;
    const int w = t >> 6;                 // wave 0..7
    const int blk = blockIdx.x;
    const int gw = blk * 8 + w;           // 0..255
    const bool active = (gw < 250);       // waves 250..255 idle in phase A

    __shared__ float Ab[3][2176];         // a triple buffer, 32 rows x 68
    __shared__ float fb[8][16][36];       // per-wave f tile (K=32 + pad)
    __shared__ float red2[2][8][1024];    // per-mt, per-wave proj partials
    __shared__ float rbuf[32 * 68];       // r, padded stride 68

    for (int i = t; i < 2048; i += 512) Ab[0][(i >> 6) * 68 + (i & 63)] = state[i];
    if (!active) {                        // idle waves' red2 stays zero forever
        for (int i = l; i < 1024; i += 64) { red2[0][w][i] = 0.f; red2[1][w][i] = 0.f; }
    }

    const int nr = l & 15;
    const int c0 = (l >> 4) << 3;
    const int cA = gw * 2;                 // chunk ids (cA,cA+1), same net
    const float* W = (cA < 250) ? Wu : Wv;
    const int glA = ((cA < 250) ? cA : cA - 250) * 32;

    // ---- persistent fragments, pinned into VGPRs ----
    bf16x8 wf[2][2][4][2], pf[2][4], sfw[2];
    if (active) {
        #pragma unroll
        for (int ch = 0; ch < 2; ch++)
            #pragma unroll
            for (int th = 0; th < 2; th++)
                #pragma unroll
                for (int rb = 0; rb < 4; rb++)
                    #pragma unroll
                    for (int kt = 0; kt < 2; kt++) {
                        const float* s = W + (size_t)(rb * 8000 + glA + ch * 32 + th * 16 + nr) * 64
                                           + kt * 32 + c0;
                        bf16x8 o;
                        #pragma unroll
                        for (int j = 0; j < 8; j++) o[j] = (__bf16)s[j];
                        wf[ch][th][rb][kt] = o;
                    }
        #pragma unroll
        for (int ch = 0; ch < 2; ch++)
            #pragma unroll
            for (int pt = 0; pt < 4; pt++) {
                const float* s = Pp + (size_t)(pt * 16 + nr) * 16000 + (cA + ch) * 32 + c0;
                bf16x8 o;
                #pragma unroll
                for (int j = 0; j < 8; j++) o[j] = (__bf16)s[j];
                pf[ch][pt] = o;
            }
    }
    {   // wave's solve tile: mtS = w>>2, ptS = w&3 ; S = inv2 - I/3
        const int ptS = w & 3;
        #pragma unroll
        for (int kt = 0; kt < 2; kt++) {
            int p = ptS * 16 + nr;
            const float* s = inv2 + (size_t)p * 64 + kt * 32 + c0;
            bf16x8 o;
            #pragma unroll
            for (int j = 0; j < 8; j++) {
                float v = s[j] - ((p == kt * 32 + c0 + j) ? (1.0f / 3.0f) : 0.0f);
                o[j] = (__bf16)v;
            }
            sfw[kt] = o;
        }
    }
    // pin everything (opaque defs -> no rematerialization inside the loop)
    #pragma unroll
    for (int ch = 0; ch < 2; ch++) {
        #pragma unroll
        for (int th = 0; th < 2; th++)
            #pragma unroll
            for (int rb = 0; rb < 4; rb++)
                #pragma unroll
                for (int kt = 0; kt < 2; kt++) PINV(wf[ch][th][rb][kt]);
        #pragma unroll
        for (int pt = 0; pt < 4; pt++) PINV(pf[ch][pt]);
    }
    PINV(sfw[0]); PINV(sfw[1]);
    __syncthreads();

    int ia_prev = 2, ia_cur = 0, ia_next = 1;
    float fprev[4];                       // f_prev for elems 4t..4t+3

    for (int k = 0; k < NSTEP; k++) {
        const int par = k & 1;
        unsigned* pslot = pbuf + (size_t)par * (NBLK * 1024) + blk * 1024;

        // ================= phase A: rhs partials =================
        if (active) {
            const int col = l & 15, q4 = l >> 4;
            #pragma unroll
            for (int mt = 0; mt < 2; mt++) {
                bf16x8 ahi[2], alo[2];
                {
                    const float* ac = Ab[ia_cur];
                    #pragma unroll
                    for (int kt = 0; kt < 2; kt++) {
                        bf16x8 hv, lv;
                        #pragma unroll
                        for (int j = 0; j < 8; j++) {
                            float x = ac[(mt * 16 + nr) * 68 + kt * 32 + c0 + j];
                            __bf16 h = (__bf16)x;
                            hv[j] = h;
                            lv[j] = (__bf16)(x - (float)h);
                        }
                        ahi[kt] = hv;
                        alo[kt] = lv;
                    }
                }
                f32x4 racc[4] = {{0.f,0.f,0.f,0.f},{0.f,0.f,0.f,0.f},
                                 {0.f,0.f,0.f,0.f},{0.f,0.f,0.f,0.f}};
                #pragma unroll
                for (int ch = 0; ch < 2; ch++) {
                    #pragma unroll
                    for (int th = 0; th < 2; th++) {
                        f32x4 z[4];
                        #pragma unroll
                        for (int rb = 0; rb < 4; rb++) {
                            f32x4 acc = {0.f, 0.f, 0.f, 0.f};
                            #pragma unroll
                            for (int kt = 0; kt < 2; kt++) {
                                acc = __builtin_amdgcn_mfma_f32_16x16x32_bf16(ahi[kt], wf[ch][th][rb][kt], acc, 0, 0, 0);
                                acc = __builtin_amdgcn_mfma_f32_16x16x32_bf16(alo[kt], wf[ch][th][rb][kt], acc, 0, 0, 0);
                            }
                            z[rb] = acc;
                        }
                        #pragma unroll
                        for (int r = 0; r < 4; r++) {
                            float f = z[0][r] * z[2][r] + z[1][r] * z[3][r];
                            fb[w][q4 * 4 + r][th * 16 + col] = f;   // intra-wave only
                        }
                    }
                    bf16x8 ff;
                    #pragma unroll
                    for (int j = 0; j < 8; j++) ff[j] = (__bf16)fb[w][nr][c0 + j];
                    #pragma unroll
                    for (int pt = 0; pt < 4; pt++)
                        racc[pt] = __builtin_amdgcn_mfma_f32_16x16x32_bf16(ff, pf[ch][pt], racc[pt], 0, 0, 0);
                }
                #pragma unroll
                for (int pt = 0; pt < 4; pt++)
                    #pragma unroll
                    for (int r = 0; r < 4; r++)
                        red2[mt][w][(q4 * 4 + r) * 64 + pt * 16 + col] = racc[pt][r];
            }
        }
        __syncthreads();

        // block partial (2048 elems) -> packed bf16 pairs, one slot
        #pragma unroll
        for (int mt = 0; mt < 2; mt++) {
            float s0 = 0.f, s1 = 0.f;
            #pragma unroll
            for (int w8 = 0; w8 < 8; w8++) {
                float2 p = *(const float2*)&red2[mt][w8][2 * t];
                s0 += p.x;
                s1 += p.y;
            }
            gstore32(&pslot[mt * 512 + t], pack2(s0, s1));
        }
        __syncthreads();                       // drains ALL waves' stores (vmcnt 0)

        // flag publish
        if (t == 0) gstore32(&flags[blk], (unsigned)(k + 1));

        // rbase hoist: LDS reads + VALU hide under flag flight / poll
        float rb_[4];
        const int bB = (4 * t) >> 6, p0B = (4 * t) & 63;
        {
            #pragma unroll
            for (int jj = 0; jj < 4; jj++) {
                int row = bB * 68 + p0B + jj;
                float av = Ab[ia_cur][row];
                rb_[jj] = (k == 0) ? av
                                   : (4.f * av - Ab[ia_prev][row] - 2.f * DTC * fprev[jj]);
            }
        }

        // all-wave poll (no post-poll sync needed)
        {
            const unsigned target = (unsigned)(k + 1);
            for (;;) {
                unsigned v = gload32(&flags[l & (NBLK - 1)]);
                if (__all(v >= target)) break;
                __builtin_amdgcn_s_sleep(1);
            }
            asm volatile("" ::: "memory");     // keep gather below the poll
        }

        // ========= redundant reduce: f elems 4t..4t+3 = -sum over 32 slots =========
        float fv[4];
        {
            const u64t* pb = (const u64t*)(pbuf + (size_t)par * (NBLK * 1024));
            float s0 = 0.f, s1 = 0.f, s2 = 0.f, s3 = 0.f;
            #pragma unroll
            for (int s = 0; s < NBLK; s++) {
                u64t v = gload64(pb + (size_t)s * 512 + t);
                unsigned lo = (unsigned)v, hi = (unsigned)(v >> 32);
                s0 += __uint_as_float(lo << 16);
                s1 += __uint_as_float(lo & 0xffff0000u);
                s2 += __uint_as_float(hi << 16);
                s3 += __uint_as_float(hi & 0xffff0000u);
            }
            fv[0] = -s0; fv[1] = -s1; fv[2] = -s2; fv[3] = -s3;
        }

        // ================= phase B: BDF2 combine + distributed solve =================
        {
            const float cf = (k == 0) ? DTC : 4.f * DTC;
            #pragma unroll
            for (int jj = 0; jj < 4; jj++) {
                float f = fv[jj];
                rbuf[bB * 68 + p0B + jj] = rb_[jj] + cf * f;
                fprev[jj] = f;
            }
        }
        __syncthreads();

        {   // wave (mtS = w>>2, ptS = w&3): a_next tile = cb*r + (r @ S^T) tile
            const int mtS = w >> 2, ptS = w & 3;
            const int col = l & 15, q4 = l >> 4;
            bf16x8 S0, S1;
            float cb;
            if (k == 0) {                   // S1 = inv1 - I, cb = 1 (once)
                #pragma unroll
                for (int kt = 0; kt < 2; kt++) {
                    int p = ptS * 16 + nr;
                    const float* s = inv1 + (size_t)p * 64 + kt * 32 + c0;
                    bf16x8 o;
                    #pragma unroll
                    for (int j = 0; j < 8; j++) {
                        float v = s[j] - ((p == kt * 32 + c0 + j) ? 1.0f : 0.0f);
                        o[j] = (__bf16)v;
                    }
                    if (kt == 0) S0 = o;
                    else         S1 = o;
                }
                cb = 1.0f;
            } else {
                S0 = sfw[0]; S1 = sfw[1];
                cb = 1.0f / 3.0f;
            }
            bf16x8 rhi[2], rlo[2];
            #pragma unroll
            for (int kt = 0; kt < 2; kt++) {
                bf16x8 hv, lv;
                #pragma unroll
                for (int j = 0; j < 8; j++) {
                    float x = rbuf[(mtS * 16 + nr) * 68 + kt * 32 + c0 + j];
                    __bf16 h = (__bf16)x;
                    hv[j] = h;
                    lv[j] = (__bf16)(x - (float)h);
                }
                rhi[kt] = hv;
                rlo[kt] = lv;
            }
            f32x4 acc;
            #pragma unroll
            for (int r = 0; r < 4; r++)
                acc[r] = rbuf[(mtS * 16 + q4 * 4 + r) * 68 + ptS * 16 + col] * cb;
            acc = __builtin_amdgcn_mfma_f32_16x16x32_bf16(rhi[0], S0, acc, 0, 0, 0);
            acc = __builtin_amdgcn_mfma_f32_16x16x32_bf16(rlo[0], S0, acc, 0, 0, 0);
            acc = __builtin_amdgcn_mfma_f32_16x16x32_bf16(rhi[1], S1, acc, 0, 0, 0);
            acc = __builtin_amdgcn_mfma_f32_16x16x32_bf16(rlo[1], S1, acc, 0, 0, 0);
            #pragma unroll
            for (int r = 0; r < 4; r++)
                Ab[ia_next][(mtS * 16 + q4 * 4 + r) * 68 + ptS * 16 + col] = acc[r];
        }
        __syncthreads();

        if (k == NSTEP - 1 && blk == 0) {
            for (int i = t; i < 2048; i += 512)
                out[i] = (Ab[ia_next][(i >> 6) * 68 + (i & 63)] - state[i]) * INV_DT_SKIP;
        }

        int tmp = ia_prev; ia_prev = ia_cur; ia_cur = ia_next; ia_next = tmp;
    }
}

// ---------------------------------------------------------------------------
extern "C" void kernel_launch(void* const* d_in, const int* in_sizes, int n_in,
                              void* d_out, int out_size, void* d_ws, size_t ws_size,
                              hipStream_t stream) {
    const float* state = (const float*)d_in[0];   // (32, 64)
    const float* Ap    = (const float*)d_in[1];   // (64, 64)
    const float* Wu    = (const float*)d_in[2];   // (32000, 64)
    const float* Wv    = (const float*)d_in[3];   // (32000, 64)
    const float* Pp    = (const float*)d_in[4];   // (64, 16000)
    float* out = (float*)d_out;
    float* ws  = (float*)d_ws;

    float* inv1 = ws;                               // 4096 floats
    float* inv2 = ws + 4096;                        // 4096 floats
    unsigned* flags = (unsigned*)(ws + 8192);       // NBLK u32 (pad to 64)
    unsigned* pbuf  = (unsigned*)(ws + 8192 + 64);  // 2 x 32 x 1024 u32

    hipLaunchKernelGGL(kzero, dim3(1), dim3(64), 0, stream, flags);
    hipLaunchKernelGGL(kinv, dim3(2), dim3(256), 0, stream, Ap, inv1, inv2);
    hipLaunchKernelGGL(kmain, dim3(NBLK), dim3(512), 0, stream,
                       state, Wu, Wv, Pp, inv1, inv2, pbuf, flags, out);
}

// Round 7
// 544.257 us; speedup vs baseline: 1.3714x; 1.3116x over previous
//
#include <hip/hip_runtime.h>

#define DTC 0.02f
#define INV_DT_SKIP 2.5f            // 1/(0.02*20)
#define NBLK 32
#define NSTEP 50

typedef __attribute__((ext_vector_type(8))) __bf16 bf16x8;
typedef __attribute__((ext_vector_type(4))) float f32x4;
typedef __attribute__((ext_vector_type(8))) unsigned short us8;
typedef unsigned long long u64t;

__device__ inline unsigned short f2bf(float x) {        // RNE fp32->bf16
    unsigned u = __float_as_uint(x);
    unsigned r = u + 0x7FFF + ((u >> 16) & 1u);
    return (unsigned short)(r >> 16);
}
__device__ inline float bf2f(unsigned short h) {
    return __uint_as_float(((unsigned)h) << 16);
}
__device__ inline unsigned pack2(float a, float b) {
    return (unsigned)f2bf(a) | ((unsigned)f2bf(b) << 16);
}
// Agent-scoped (cross-XCD, coherence-point) RELAXED accesses. Ordering is
// carried by the vmcnt(0) drain inside __syncthreads before flag publish,
// plus a compiler barrier after poll success (stops load hoisting).
__device__ inline void gstore32(unsigned* p, unsigned v) {
    __hip_atomic_store(p, v, __ATOMIC_RELAXED, __HIP_MEMORY_SCOPE_AGENT);
}
__device__ inline unsigned gload32(const unsigned* p) {
    return __hip_atomic_load(p, __ATOMIC_RELAXED, __HIP_MEMORY_SCOPE_AGENT);
}
__device__ inline u64t gload64(const u64t* p) {
    return __hip_atomic_load(p, __ATOMIC_RELAXED, __HIP_MEMORY_SCOPE_AGENT);
}
// Pin a 16B fragment into VGPRs: opaque def prevents the allocator from
// rematerializing the global load + bf16 conversion every loop iteration.
#define PINV(x) asm volatile("" : "+v"(x))

// ---------------------------------------------------------------------------
// Neumann inverses (verified rounds 1-7). inv1 = (I-dt*Ap)^-1,
// inv2 = (3I-2dt*Ap)^-1.
// ---------------------------------------------------------------------------
__global__ __launch_bounds__(256) void kinv(const float* __restrict__ Ap,
                                            float* __restrict__ inv1,
                                            float* __restrict__ inv2) {
    const int t = threadIdx.x;
    const float coef  = (blockIdx.x == 0) ? DTC : (2.0f * DTC / 3.0f);
    const float scale = (blockIdx.x == 0) ? 1.0f : (1.0f / 3.0f);
    float* outp = (blockIdx.x == 0) ? inv1 : inv2;

    __shared__ float ET[64 * 68];
    __shared__ float XA[64 * 68];
    __shared__ float XB[64 * 68];

    for (int idx = t; idx < 4096; idx += 256) {
        int r = idx >> 6, c = idx & 63;
        float e = coef * Ap[idx];
        ET[c * 68 + r] = e;
        XA[r * 68 + c] = ((r == c) ? 1.0f : 0.0f) + e;
    }
    __syncthreads();

    const int rr = (t >> 4) << 2;
    const int cc = (t & 15) << 2;
    float* bufs[2] = {XA, XB};
    for (int it = 0; it < 3; it++) {
        const float* Xin = bufs[it & 1];
        float* Xout = bufs[(it + 1) & 1];
        float acc[4][4];
        #pragma unroll
        for (int i = 0; i < 4; i++)
            #pragma unroll
            for (int j = 0; j < 4; j++)
                acc[i][j] = ((rr + i) == (cc + j)) ? 1.0f : 0.0f;
        for (int k = 0; k < 64; k++) {
            float4 e4 = *(const float4*)&ET[k * 68 + rr];
            float4 x4 = *(const float4*)&Xin[k * 68 + cc];
            float ev[4] = {e4.x, e4.y, e4.z, e4.w};
            float xv[4] = {x4.x, x4.y, x4.z, x4.w};
            #pragma unroll
            for (int i = 0; i < 4; i++)
                #pragma unroll
                for (int j = 0; j < 4; j++)
                    acc[i][j] += ev[i] * xv[j];
        }
        __syncthreads();
        #pragma unroll
        for (int i = 0; i < 4; i++)
            #pragma unroll
            for (int j = 0; j < 4; j++)
                Xout[(rr + i) * 68 + cc + j] = acc[i][j];
        __syncthreads();
    }
    const float* Xf = bufs[1];
    for (int idx = t; idx < 4096; idx += 256) {
        int r = idx >> 6, c = idx & 63;
        outp[idx] = scale * Xf[r * 68 + c];
    }
}

__global__ void kzero(unsigned* __restrict__ flags) {
    if (threadIdx.x < NBLK) flags[threadIdx.x] = 0u;
}

// ---------------------------------------------------------------------------
// Persistent kernel, 32 blocks, one flag-barrier per step, all-RELAXED.
// Wave gw = blk*8+w owns chunks 2gw, 2gw+1 (gw<250). W/P/S fragments pinned
// in VGPRs (PINV) for the whole kernel. Per step:
//   Phase A: z = a@W^T hi/lo bf16 MFMA, f=u*dx+v*dy, intra-wave LDS C->A
//   relayout, proj MFMA (both chunks, both mt) -> red2 -> sync -> block
//   reduce -> bf16-packed slot (parity double-buffered) -> sync (drains
//   stores) -> flag publish; ALL waves poll all 32 flags (no post-poll
//   sync) -> gather 32 slots (coalesced u64 agent loads) -> f in regs ->
//   BDF2 r -> LDS -> sync -> distributed solve (wave -> one (mt,pt) tile)
//   -> sync. Block 0 writes out at last step.
// pbuf parity WAR safety: observing flag(k+1) from every block implies that
// block finished its step-k gather (program order + vmcnt drain), which
// last read parity(k+1).
// ---------------------------------------------------------------------------
__global__ __launch_bounds__(512, 2)
void kmain(const float* __restrict__ state,
           const float* __restrict__ Wu,
           const float* __restrict__ Wv,
           const float* __restrict__ Pp,
           const float* __restrict__ inv1,
           const float* __restrict__ inv2,
           unsigned* __restrict__ pbuf,     // 2 parities x 32 slots x 1024 u32
           unsigned* __restrict__ flags,    // NBLK flag words
           float* __restrict__ out) {
    const int t = threadIdx.x;
    const int l = t & 63;
    const int w = t >> 6;                 // wave 0..7
    const int blk = blockIdx.x;
    const int gw = blk * 8 + w;           // 0..255
    const bool active = (gw < 250);       // waves 250..255 idle in phase A

    __shared__ float Ab[3][2176];         // a triple buffer, 32 rows x 68
    __shared__ float fb[8][16][36];       // per-wave f tile (K=32 + pad)
    __shared__ float red2[2][8][1024];    // per-mt, per-wave proj partials
    __shared__ float rbuf[32 * 68];       // r, padded stride 68

    for (int i = t; i < 2048; i += 512) Ab[0][(i >> 6) * 68 + (i & 63)] = state[i];
    if (!active) {                        // idle waves' red2 stays zero forever
        for (int i = l; i < 1024; i += 64) { red2[0][w][i] = 0.f; red2[1][w][i] = 0.f; }
    }

    const int nr = l & 15;
    const int c0 = (l >> 4) << 3;
    const int cA = gw * 2;                 // chunk ids (cA,cA+1), same net
    const float* W = (cA < 250) ? Wu : Wv;
    const int glA = ((cA < 250) ? cA : cA - 250) * 32;

    // ---- persistent fragments, pinned into VGPRs ----
    bf16x8 wf[2][2][4][2], pf[2][4], sfw[2];
    if (active) {
        #pragma unroll
        for (int ch = 0; ch < 2; ch++)
            #pragma unroll
            for (int th = 0; th < 2; th++)
                #pragma unroll
                for (int rb = 0; rb < 4; rb++)
                    #pragma unroll
                    for (int kt = 0; kt < 2; kt++) {
                        const float* s = W + (size_t)(rb * 8000 + glA + ch * 32 + th * 16 + nr) * 64
                                           + kt * 32 + c0;
                        us8 o;
                        #pragma unroll
                        for (int j = 0; j < 8; j++) o[j] = f2bf(s[j]);
                        wf[ch][th][rb][kt] = __builtin_bit_cast(bf16x8, o);
                    }
        #pragma unroll
        for (int ch = 0; ch < 2; ch++)
            #pragma unroll
            for (int pt = 0; pt < 4; pt++) {
                const float* s = Pp + (size_t)(pt * 16 + nr) * 16000 + (cA + ch) * 32 + c0;
                us8 o;
                #pragma unroll
                for (int j = 0; j < 8; j++) o[j] = f2bf(s[j]);
                pf[ch][pt] = __builtin_bit_cast(bf16x8, o);
            }
    }
    {   // wave's solve tile: mtS = w>>2, ptS = w&3 ; S = inv2 - I/3
        const int ptS = w & 3;
        #pragma unroll
        for (int kt = 0; kt < 2; kt++) {
            int p = ptS * 16 + nr;
            const float* s = inv2 + (size_t)p * 64 + kt * 32 + c0;
            us8 o;
            #pragma unroll
            for (int j = 0; j < 8; j++) {
                float v = s[j] - ((p == kt * 32 + c0 + j) ? (1.0f / 3.0f) : 0.0f);
                o[j] = f2bf(v);
            }
            sfw[kt] = __builtin_bit_cast(bf16x8, o);
        }
    }
    // pin everything (opaque defs -> no rematerialization inside the loop)
    #pragma unroll
    for (int ch = 0; ch < 2; ch++) {
        #pragma unroll
        for (int th = 0; th < 2; th++)
            #pragma unroll
            for (int rb = 0; rb < 4; rb++)
                #pragma unroll
                for (int kt = 0; kt < 2; kt++) PINV(wf[ch][th][rb][kt]);
        #pragma unroll
        for (int pt = 0; pt < 4; pt++) PINV(pf[ch][pt]);
    }
    PINV(sfw[0]); PINV(sfw[1]);
    __syncthreads();

    int ia_prev = 2, ia_cur = 0, ia_next = 1;
    float fprev[4];                       // f_prev for elems 4t..4t+3

    for (int k = 0; k < NSTEP; k++) {
        const int par = k & 1;
        unsigned* pslot = pbuf + (size_t)par * (NBLK * 1024) + blk * 1024;

        // ================= phase A: rhs partials =================
        if (active) {
            const int col = l & 15, q4 = l >> 4;
            #pragma unroll
            for (int mt = 0; mt < 2; mt++) {
                bf16x8 ahi[2], alo[2];
                {
                    const float* ac = Ab[ia_cur];
                    #pragma unroll
                    for (int kt = 0; kt < 2; kt++) {
                        us8 hv, lv;
                        #pragma unroll
                        for (int j = 0; j < 8; j++) {
                            float x = ac[(mt * 16 + nr) * 68 + kt * 32 + c0 + j];
                            unsigned short h = f2bf(x);
                            hv[j] = h;
                            lv[j] = f2bf(x - bf2f(h));
                        }
                        ahi[kt] = __builtin_bit_cast(bf16x8, hv);
                        alo[kt] = __builtin_bit_cast(bf16x8, lv);
                    }
                }
                f32x4 racc[4] = {{0.f,0.f,0.f,0.f},{0.f,0.f,0.f,0.f},
                                 {0.f,0.f,0.f,0.f},{0.f,0.f,0.f,0.f}};
                #pragma unroll
                for (int ch = 0; ch < 2; ch++) {
                    #pragma unroll
                    for (int th = 0; th < 2; th++) {
                        f32x4 z[4];
                        #pragma unroll
                        for (int rb = 0; rb < 4; rb++) {
                            f32x4 acc = {0.f, 0.f, 0.f, 0.f};
                            #pragma unroll
                            for (int kt = 0; kt < 2; kt++) {
                                acc = __builtin_amdgcn_mfma_f32_16x16x32_bf16(ahi[kt], wf[ch][th][rb][kt], acc, 0, 0, 0);
                                acc = __builtin_amdgcn_mfma_f32_16x16x32_bf16(alo[kt], wf[ch][th][rb][kt], acc, 0, 0, 0);
                            }
                            z[rb] = acc;
                        }
                        #pragma unroll
                        for (int r = 0; r < 4; r++) {
                            float f = z[0][r] * z[2][r] + z[1][r] * z[3][r];
                            fb[w][q4 * 4 + r][th * 16 + col] = f;   // intra-wave only
                        }
                    }
                    bf16x8 ff;
                    {
                        us8 fv8;
                        #pragma unroll
                        for (int j = 0; j < 8; j++) fv8[j] = f2bf(fb[w][nr][c0 + j]);
                        ff = __builtin_bit_cast(bf16x8, fv8);
                    }
                    #pragma unroll
                    for (int pt = 0; pt < 4; pt++)
                        racc[pt] = __builtin_amdgcn_mfma_f32_16x16x32_bf16(ff, pf[ch][pt], racc[pt], 0, 0, 0);
                }
                #pragma unroll
                for (int pt = 0; pt < 4; pt++)
                    #pragma unroll
                    for (int r = 0; r < 4; r++)
                        red2[mt][w][(q4 * 4 + r) * 64 + pt * 16 + col] = racc[pt][r];
            }
        }
        __syncthreads();

        // block partial (2048 elems) -> packed bf16 pairs, one slot
        #pragma unroll
        for (int mt = 0; mt < 2; mt++) {
            float s0 = 0.f, s1 = 0.f;
            #pragma unroll
            for (int w8 = 0; w8 < 8; w8++) {
                s0 += red2[mt][w8][2 * t];
                s1 += red2[mt][w8][2 * t + 1];
            }
            gstore32(&pslot[mt * 512 + t], pack2(s0, s1));
        }
        __syncthreads();                       // drains ALL waves' stores (vmcnt 0)

        // flag publish + all-wave poll (no post-poll sync needed)
        if (t == 0) gstore32(&flags[blk], (unsigned)(k + 1));
        {
            const unsigned target = (unsigned)(k + 1);
            for (;;) {
                unsigned v = gload32(&flags[l & (NBLK - 1)]);
                if (__all(v >= target)) break;
                __builtin_amdgcn_s_sleep(1);
            }
            asm volatile("" ::: "memory");     // keep gather below the poll
        }

        // ========= redundant reduce: f elems 4t..4t+3 = -sum over 32 slots =========
        float fv[4];
        {
            const u64t* pb = (const u64t*)(pbuf + (size_t)par * (NBLK * 1024));
            float s0 = 0.f, s1 = 0.f, s2 = 0.f, s3 = 0.f;
            #pragma unroll
            for (int s = 0; s < NBLK; s++) {
                u64t v = gload64(pb + (size_t)s * 512 + t);
                unsigned lo = (unsigned)v, hi = (unsigned)(v >> 32);
                s0 += __uint_as_float(lo << 16);
                s1 += __uint_as_float(lo & 0xffff0000u);
                s2 += __uint_as_float(hi << 16);
                s3 += __uint_as_float(hi & 0xffff0000u);
            }
            fv[0] = -s0; fv[1] = -s1; fv[2] = -s2; fv[3] = -s3;
        }

        // ================= phase B: BDF2 combine + distributed solve =================
        {
            const int b = (4 * t) >> 6, p0 = (4 * t) & 63;
            #pragma unroll
            for (int jj = 0; jj < 4; jj++) {
                float f = fv[jj];
                int row = b * 68 + p0 + jj;
                float av = Ab[ia_cur][row];
                float rv = (k == 0) ? (av + DTC * f)
                                    : (4.f * av - Ab[ia_prev][row]
                                       + 4.f * DTC * f - 2.f * DTC * fprev[jj]);
                rbuf[row] = rv;
                fprev[jj] = f;
            }
        }
        __syncthreads();

        {   // wave (mtS = w>>2, ptS = w&3): a_next tile = cb*r + (r @ S^T) tile
            const int mtS = w >> 2, ptS = w & 3;
            const int col = l & 15, q4 = l >> 4;
            bf16x8 S0, S1;
            float cb;
            if (k == 0) {                   // S1 = inv1 - I, cb = 1 (once)
                #pragma unroll
                for (int kt = 0; kt < 2; kt++) {
                    int p = ptS * 16 + nr;
                    const float* s = inv1 + (size_t)p * 64 + kt * 32 + c0;
                    us8 o;
                    #pragma unroll
                    for (int j = 0; j < 8; j++) {
                        float v = s[j] - ((p == kt * 32 + c0 + j) ? 1.0f : 0.0f);
                        o[j] = f2bf(v);
                    }
                    if (kt == 0) S0 = __builtin_bit_cast(bf16x8, o);
                    else         S1 = __builtin_bit_cast(bf16x8, o);
                }
                cb = 1.0f;
            } else {
                S0 = sfw[0]; S1 = sfw[1];
                cb = 1.0f / 3.0f;
            }
            bf16x8 rhi[2], rlo[2];
            #pragma unroll
            for (int kt = 0; kt < 2; kt++) {
                us8 hv, lv;
                #pragma unroll
                for (int j = 0; j < 8; j++) {
                    float x = rbuf[(mtS * 16 + nr) * 68 + kt * 32 + c0 + j];
                    unsigned short h = f2bf(x);
                    hv[j] = h;
                    lv[j] = f2bf(x - bf2f(h));
                }
                rhi[kt] = __builtin_bit_cast(bf16x8, hv);
                rlo[kt] = __builtin_bit_cast(bf16x8, lv);
            }
            f32x4 acc;
            #pragma unroll
            for (int r = 0; r < 4; r++)
                acc[r] = rbuf[(mtS * 16 + q4 * 4 + r) * 68 + ptS * 16 + col] * cb;
            acc = __builtin_amdgcn_mfma_f32_16x16x32_bf16(rhi[0], S0, acc, 0, 0, 0);
            acc = __builtin_amdgcn_mfma_f32_16x16x32_bf16(rlo[0], S0, acc, 0, 0, 0);
            acc = __builtin_amdgcn_mfma_f32_16x16x32_bf16(rhi[1], S1, acc, 0, 0, 0);
            acc = __builtin_amdgcn_mfma_f32_16x16x32_bf16(rlo[1], S1, acc, 0, 0, 0);
            #pragma unroll
            for (int r = 0; r < 4; r++)
                Ab[ia_next][(mtS * 16 + q4 * 4 + r) * 68 + ptS * 16 + col] = acc[r];
        }
        __syncthreads();

        if (k == NSTEP - 1 && blk == 0) {
            for (int i = t; i < 2048; i += 512)
                out[i] = (Ab[ia_next][(i >> 6) * 68 + (i & 63)] - state[i]) * INV_DT_SKIP;
        }

        int tmp = ia_prev; ia_prev = ia_cur; ia_cur = ia_next; ia_next = tmp;
    }
}

// ---------------------------------------------------------------------------
extern "C" void kernel_launch(void* const* d_in, const int* in_sizes, int n_in,
                              void* d_out, int out_size, void* d_ws, size_t ws_size,
                              hipStream_t stream) {
    const float* state = (const float*)d_in[0];   // (32, 64)
    const float* Ap    = (const float*)d_in[1];   // (64, 64)
    const float* Wu    = (const float*)d_in[2];   // (32000, 64)
    const float* Wv    = (const float*)d_in[3];   // (32000, 64)
    const float* Pp    = (const float*)d_in[4];   // (64, 16000)
    float* out = (float*)d_out;
    float* ws  = (float*)d_ws;

    float* inv1 = ws;                               // 4096 floats
    float* inv2 = ws + 4096;                        // 4096 floats
    unsigned* flags = (unsigned*)(ws + 8192);       // NBLK u32 (pad to 64)
    unsigned* pbuf  = (unsigned*)(ws + 8192 + 64);  // 2 x 32 x 1024 u32

    hipLaunchKernelGGL(kzero, dim3(1), dim3(64), 0, stream, flags);
    hipLaunchKernelGGL(kinv, dim3(2), dim3(256), 0, stream, Ap, inv1, inv2);
    hipLaunchKernelGGL(kmain, dim3(NBLK), dim3(512), 0, stream,
                       state, Wu, Wv, Pp, inv1, inv2, pbuf, flags, out);
}